// Round 3
// baseline (253.259 us; speedup 1.0000x reference)
//
#include <hip/hip_runtime.h>
#include <math.h>

#define THREADS 256
#define NBLOCKS 2048

// ---- monotone float <-> uint encoding (order-preserving) ----
__device__ __forceinline__ unsigned enc_f(float f) {
    unsigned b = __float_as_uint(f);
    return (b & 0x80000000u) ? ~b : (b | 0x80000000u);
}
__device__ __forceinline__ float dec_f(unsigned u) {
    unsigned b = (u & 0x80000000u) ? (u ^ 0x80000000u) : ~u;
    return __uint_as_float(b);
}
#define ENC_NEG_INF 0x007FFFFFu   // enc(-inf): identity for max
#define ENC_POS_INF 0xFF800000u   // enc(+inf): identity for min

// ws layout (unsigned*): [0..7] gmax(max) | [8..15] pmin(min) | [16..23] zmin(min)
//                        [24..31] zmax(max) | [32..33] double acc | [34] done-counter

__global__ void k_init(unsigned* __restrict__ ws) {
    int t = threadIdx.x;
    if (t < 32) ws[t] = (t < 8 || t >= 24) ? ENC_NEG_INF : ENC_POS_INF;
    else if (t == 32) { *(double*)(ws + 32) = 0.0; ws[34] = 0u; }
}

__global__ __launch_bounds__(THREADS) void k_stats(
        const float* __restrict__ coord, const int* __restrict__ segment,
        const int* __restrict__ offset, unsigned* __restrict__ ws, int n, int nb) {
    __shared__ unsigned s_stats[32];
    const int tid = threadIdx.x;
    if (tid < 32) s_stats[tid] = (tid < 8 || tid >= 24) ? ENC_NEG_INF : ENC_POS_INF;
    int roff[8];                       // offsets in REGISTERS (round-1 bug: LDS re-read 8x/point)
    #pragma unroll
    for (int j = 0; j < 8; ++j) roff[j] = (j < nb) ? offset[j] : 0x7FFFFFFF;
    __syncthreads();

    const int nq     = n >> 2;
    const int qchunk = (nq + (int)gridDim.x - 1) / (int)gridDim.x;
    const int qstart = blockIdx.x * qchunk;
    const int qend   = min(nq, qstart + qchunk);
    const float4* c4 = (const float4*)coord;
    const int4*   s4 = (const int4*)segment;

    float lg = -INFINITY, lp = INFINITY, lmn = INFINITY, lmx = -INFINITY;
    int fastb = -1;

    #define FLUSH_TO(bb, g_, p_, mn_, mx_) do { \
        atomicMax(&s_stats[      (bb)], enc_f(g_));  \
        atomicMin(&s_stats[ 8  + (bb)], enc_f(p_));  \
        atomicMin(&s_stats[16  + (bb)], enc_f(mn_)); \
        atomicMax(&s_stats[24  + (bb)], enc_f(mx_)); } while (0)

    if (qstart < qend) {
        int ia = qstart << 2, ib = (qend << 2) - 1;
        int ba = 0, bb = 0;
        #pragma unroll
        for (int j = 0; j < 8; ++j) { ba += (ia >= roff[j]); bb += (ib >= roff[j]); }
        if (ba == bb) {
            // ---- fast path: whole block chunk in one cloud ----
            fastb = ba;
            for (int q = qstart + tid; q < qend; q += THREADS) {
                float4 f0 = c4[3*q], f1 = c4[3*q+1], f2 = c4[3*q+2];
                int4   sg = s4[q];
                float z0 = f0.z, z1 = f1.y, z2 = f2.x, z3 = f2.w;
                lmn = fminf(fminf(fminf(lmn, z0), z1), fminf(z2, z3));
                lmx = fmaxf(fmaxf(fmaxf(lmx, z0), z1), fmaxf(z2, z3));
                lg = fmaxf(lg, (sg.x == 0) ? z0 : -INFINITY);
                lg = fmaxf(lg, (sg.y == 0) ? z1 : -INFINITY);
                lg = fmaxf(lg, (sg.z == 0) ? z2 : -INFINITY);
                lg = fmaxf(lg, (sg.w == 0) ? z3 : -INFINITY);
                lp = fminf(lp, (sg.x != 0) ? z0 : INFINITY);
                lp = fminf(lp, (sg.y != 0) ? z1 : INFINITY);
                lp = fminf(lp, (sg.z != 0) ? z2 : INFINITY);
                lp = fminf(lp, (sg.w != 0) ? z3 : INFINITY);
            }
        } else {
            // ---- slow path (<= B-1 blocks): per-point batch tracking ----
            int curb = -1;
            for (int q = qstart + tid; q < qend; q += THREADS) {
                float4 f0 = c4[3*q], f1 = c4[3*q+1], f2 = c4[3*q+2];
                int4   sg = s4[q];
                float zz[4] = { f0.z, f1.y, f2.x, f2.w };
                int   ss[4] = { sg.x, sg.y, sg.z, sg.w };
                #pragma unroll
                for (int k = 0; k < 4; ++k) {
                    int i = 4*q + k, b = 0;
                    #pragma unroll
                    for (int j = 0; j < 8; ++j) b += (i >= roff[j]);
                    if (b != curb) {
                        if (curb >= 0) FLUSH_TO(curb, lg, lp, lmn, lmx);
                        lg = -INFINITY; lp = INFINITY; lmn = INFINITY; lmx = -INFINITY;
                        curb = b;
                    }
                    lmn = fminf(lmn, zz[k]); lmx = fmaxf(lmx, zz[k]);
                    if (ss[k] == 0) lg = fmaxf(lg, zz[k]); else lp = fminf(lp, zz[k]);
                }
            }
            if (curb >= 0) FLUSH_TO(curb, lg, lp, lmn, lmx);
        }
    }
    if (fastb >= 0) {
        #pragma unroll
        for (int m = 32; m; m >>= 1) {
            lg  = fmaxf(lg,  __shfl_xor(lg,  m, 64));
            lp  = fminf(lp,  __shfl_xor(lp,  m, 64));
            lmn = fminf(lmn, __shfl_xor(lmn, m, 64));
            lmx = fmaxf(lmx, __shfl_xor(lmx, m, 64));
        }
        if ((tid & 63) == 0) FLUSH_TO(fastb, lg, lp, lmn, lmx);
    }
    // scalar tail (n % 4) — block 0 thread 0
    if (blockIdx.x == 0 && tid == 0) {
        for (int i = (n >> 2) << 2; i < n; ++i) {
            float z = coord[3*i + 2]; int s = segment[i], b = 0;
            #pragma unroll
            for (int j = 0; j < 8; ++j) b += (i >= roff[j]);
            float tg = (s == 0) ? z : -INFINITY, tp = (s != 0) ? z : INFINITY;
            FLUSH_TO(b, tg, tp, z, z);
        }
    }
    __syncthreads();
    if (tid < 32) {
        unsigned v = s_stats[tid];
        unsigned ident = (tid < 8 || tid >= 24) ? ENC_NEG_INF : ENC_POS_INF;
        if (v != ident) {
            if (tid >= 8 && tid < 24) atomicMin(&ws[tid], v);
            else                      atomicMax(&ws[tid], v);
        }
    }
}

__device__ __forceinline__ float point_loss(float p0, float p1, int s, float z, float mu) {
    float m   = fmaxf(p0, p1);
    float lse = m + logf(expf(p0 - m) + expf(p1 - m));
    float lpt = ((s == 0) ? p0 : p1) - lse;
    float pt  = expf(lpt);
    float om  = 1.0f - pt;
    float loss = -lpt * om * om;           // LOSS_WEIGHT=ALPHA=1, GAMMA=2
    float d  = z - mu;
    float cf = (z <= mu) ? 50.0f : 3.125f; // 1/(2*0.1^2), 1/(2*0.4^2)
    float w  = expf(-d * d * cf);
    if (z > mu && d > 0.8f) w = 0.1f;      // clamp: d > 2*0.4 -> MIN_VAL
    return loss * w;
}

__global__ __launch_bounds__(THREADS) void k_loss(
        const float* __restrict__ pred, const float* __restrict__ coord,
        const int* __restrict__ segment, const int* __restrict__ offset,
        unsigned* __restrict__ ws, float* __restrict__ out, int n, int nb) {
    __shared__ float s_mu[8];
    __shared__ float s_part[THREADS / 64];
    const int tid = threadIdx.x;
    int roff[8];
    #pragma unroll
    for (int j = 0; j < 8; ++j) roff[j] = (j < nb) ? offset[j] : 0x7FFFFFFF;
    if (tid < 8) {
        unsigned ug = ws[tid], up = ws[8 + tid];
        float g = dec_f(ug), p = dec_f(up);
        if (ug == ENC_NEG_INF) g = dec_f(ws[16 + tid]);  // no ground -> z.min
        if (up == ENC_POS_INF) p = dec_f(ws[24 + tid]);  // no plant  -> z.max
        s_mu[tid] = g + (p - g) * 0.5f;
    }
    __syncthreads();

    const int nq     = n >> 2;
    const int qchunk = (nq + (int)gridDim.x - 1) / (int)gridDim.x;
    const int qstart = blockIdx.x * qchunk;
    const int qend   = min(nq, qstart + qchunk);
    const float4* c4 = (const float4*)coord;
    const int4*   s4 = (const int4*)segment;
    const float4* p4 = (const float4*)pred;

    float lsum = 0.0f;
    if (qstart < qend) {
        int ia = qstart << 2, ib = (qend << 2) - 1;
        int ba = 0, bb = 0;
        #pragma unroll
        for (int j = 0; j < 8; ++j) { ba += (ia >= roff[j]); bb += (ib >= roff[j]); }
        if (ba == bb) {
            const float mu = s_mu[ba];           // hoisted: no LDS in hot loop
            for (int q = qstart + tid; q < qend; q += THREADS) {
                float4 pa = p4[2*q], pb = p4[2*q + 1];
                float4 f0 = c4[3*q], f1 = c4[3*q+1], f2 = c4[3*q+2];
                int4   sg = s4[q];
                lsum += point_loss(pa.x, pa.y, sg.x, f0.z, mu);
                lsum += point_loss(pa.z, pa.w, sg.y, f1.y, mu);
                lsum += point_loss(pb.x, pb.y, sg.z, f2.x, mu);
                lsum += point_loss(pb.z, pb.w, sg.w, f2.w, mu);
            }
        } else {
            for (int q = qstart + tid; q < qend; q += THREADS) {
                float4 pa = p4[2*q], pb = p4[2*q + 1];
                float4 f0 = c4[3*q], f1 = c4[3*q+1], f2 = c4[3*q+2];
                int4   sg = s4[q];
                float zz[4] = { f0.z, f1.y, f2.x, f2.w };
                float pp[8] = { pa.x, pa.y, pa.z, pa.w, pb.x, pb.y, pb.z, pb.w };
                int   ss[4] = { sg.x, sg.y, sg.z, sg.w };
                #pragma unroll
                for (int k = 0; k < 4; ++k) {
                    int i = 4*q + k, b = 0;
                    #pragma unroll
                    for (int j = 0; j < 8; ++j) b += (i >= roff[j]);
                    lsum += point_loss(pp[2*k], pp[2*k+1], ss[k], zz[k], s_mu[b]);
                }
            }
        }
    }
    // scalar tail (n % 4) — block 0 thread 0
    if (blockIdx.x == 0 && tid == 0) {
        for (int i = (n >> 2) << 2; i < n; ++i) {
            int b = 0;
            #pragma unroll
            for (int j = 0; j < 8; ++j) b += (i >= roff[j]);
            lsum += point_loss(pred[2*i], pred[2*i+1], segment[i], coord[3*i+2], s_mu[b]);
        }
    }

    #pragma unroll
    for (int off = 32; off > 0; off >>= 1) lsum += __shfl_down(lsum, off, 64);
    if ((tid & 63) == 0) s_part[tid >> 6] = lsum;
    __syncthreads();
    if (tid == 0) {
        float t = 0.0f;
        #pragma unroll
        for (int wv = 0; wv < THREADS / 64; ++wv) t += s_part[wv];
        double* acc = (double*)(ws + 32);
        atomicAdd(acc, (double)t);
        __threadfence();                               // release our acc-add
        unsigned c = atomicAdd(&ws[34], 1u);
        if (c == (unsigned)gridDim.x - 1u) {           // last block finalizes
            double v = atomicAdd(acc, 0.0);            // coherent read via atomic
            out[0] = (float)(v / (double)n);
        }
    }
}

extern "C" void kernel_launch(void* const* d_in, const int* in_sizes, int n_in,
                              void* d_out, int out_size, void* d_ws, size_t ws_size,
                              hipStream_t stream) {
    const float* pred    = (const float*)d_in[0];
    const float* coord   = (const float*)d_in[1];
    const int*   segment = (const int*)d_in[2];
    const int*   offset  = (const int*)d_in[3];
    const int n  = in_sizes[2];
    const int nb = in_sizes[3];

    unsigned* ws = (unsigned*)d_ws;

    hipLaunchKernelGGL(k_init,  dim3(1), dim3(64), 0, stream, ws);
    hipLaunchKernelGGL(k_stats, dim3(NBLOCKS), dim3(THREADS), 0, stream,
                       coord, segment, offset, ws, n, nb);
    hipLaunchKernelGGL(k_loss,  dim3(NBLOCKS), dim3(THREADS), 0, stream,
                       pred, coord, segment, offset, ws, (float*)d_out, n, nb);
}

// Round 4
// 182.299 us; speedup vs baseline: 1.3893x; 1.3893x over previous
//
#include <hip/hip_runtime.h>
#include <math.h>

#define THREADS 256
#define NBLOCKS 1024
#define UNROLL  8

// ---- monotone float <-> uint encoding (order-preserving) ----
__device__ __forceinline__ unsigned enc_f(float f) {
    unsigned b = __float_as_uint(f);
    return (b & 0x80000000u) ? ~b : (b | 0x80000000u);
}
__device__ __forceinline__ float dec_f(unsigned u) {
    unsigned b = (u & 0x80000000u) ? (u ^ 0x80000000u) : ~u;
    return __uint_as_float(b);
}
#define ENC_NEG_INF 0x007FFFFFu   // enc(-inf): identity for max
#define ENC_POS_INF 0xFF800000u   // enc(+inf): identity for min

// ws layout (unsigned*): [0..7] gmax(max) | [8..15] pmin(min) | [16..23] zmin(min)
//                        [24..31] zmax(max) | [32..33] double acc | [34] done-counter

__global__ void k_init(unsigned* __restrict__ ws) {
    int t = threadIdx.x;
    if (t < 32) ws[t] = (t < 8 || t >= 24) ? ENC_NEG_INF : ENC_POS_INF;
    else if (t == 32) { *(double*)(ws + 32) = 0.0; ws[34] = 0u; }
}

#define FLUSH_TO(bb, g_, p_, mn_, mx_) do { \
    atomicMax(&s_stats[      (bb)], enc_f(g_));  \
    atomicMin(&s_stats[ 8  + (bb)], enc_f(p_));  \
    atomicMin(&s_stats[16  + (bb)], enc_f(mn_)); \
    atomicMax(&s_stats[24  + (bb)], enc_f(mx_)); } while (0)

__global__ __launch_bounds__(THREADS) void k_stats(
        const float* __restrict__ coord, const int* __restrict__ segment,
        const int* __restrict__ offset, unsigned* __restrict__ ws, int n, int nb) {
    __shared__ unsigned s_stats[32];
    const int tid = threadIdx.x;
    if (tid < 32) s_stats[tid] = (tid < 8 || tid >= 24) ? ENC_NEG_INF : ENC_POS_INF;
    int roff[8];                        // offsets in registers
    #pragma unroll
    for (int j = 0; j < 8; ++j) roff[j] = (j < nb) ? offset[j] : 0x7FFFFFFF;
    __syncthreads();

    const int chunk = (n + (int)gridDim.x - 1) / (int)gridDim.x;
    const int start = blockIdx.x * chunk;
    const int end   = min(n, start + chunk);

    float lg = -INFINITY, lp = INFINITY, lmn = INFINITY, lmx = -INFINITY;

    if (start < end) {
        int ba = 0, bb = 0;
        #pragma unroll
        for (int j = 0; j < 8; ++j) { ba += (start >= roff[j]); bb += ((end - 1) >= roff[j]); }
        if (ba == bb) {
            // ---- fast path: whole chunk in one cloud; coalesced scalar loads, 8x MLP ----
            int i = start + tid;
            for (; i + (UNROLL - 1) * THREADS < end; i += UNROLL * THREADS) {
                float z[UNROLL]; int s[UNROLL];
                #pragma unroll
                for (int k = 0; k < UNROLL; ++k) z[k] = coord[3 * (i + k * THREADS) + 2];
                #pragma unroll
                for (int k = 0; k < UNROLL; ++k) s[k] = segment[i + k * THREADS];
                #pragma unroll
                for (int k = 0; k < UNROLL; ++k) {
                    lmn = fminf(lmn, z[k]);
                    lmx = fmaxf(lmx, z[k]);
                    lg  = fmaxf(lg, (s[k] == 0) ? z[k] : -INFINITY);
                    lp  = fminf(lp, (s[k] != 0) ? z[k] : INFINITY);
                }
            }
            for (; i < end; i += THREADS) {
                float z = coord[3 * i + 2]; int s = segment[i];
                lmn = fminf(lmn, z); lmx = fmaxf(lmx, z);
                lg  = fmaxf(lg, (s == 0) ? z : -INFINITY);
                lp  = fminf(lp, (s != 0) ? z : INFINITY);
            }
            // wave reduce (block-uniform path: all lanes present)
            #pragma unroll
            for (int m = 32; m; m >>= 1) {
                lg  = fmaxf(lg,  __shfl_xor(lg,  m, 64));
                lp  = fminf(lp,  __shfl_xor(lp,  m, 64));
                lmn = fminf(lmn, __shfl_xor(lmn, m, 64));
                lmx = fmaxf(lmx, __shfl_xor(lmx, m, 64));
            }
            if ((tid & 63) == 0) FLUSH_TO(ba, lg, lp, lmn, lmx);
        } else {
            // ---- slow path (<= B-1 blocks): per-point batch tracking ----
            int curb = -1;
            for (int i = start + tid; i < end; i += THREADS) {
                float z = coord[3 * i + 2]; int s = segment[i], b = 0;
                #pragma unroll
                for (int j = 0; j < 8; ++j) b += (i >= roff[j]);
                if (b != curb) {
                    if (curb >= 0) FLUSH_TO(curb, lg, lp, lmn, lmx);
                    lg = -INFINITY; lp = INFINITY; lmn = INFINITY; lmx = -INFINITY;
                    curb = b;
                }
                lmn = fminf(lmn, z); lmx = fmaxf(lmx, z);
                if (s == 0) lg = fmaxf(lg, z); else lp = fminf(lp, z);
            }
            if (curb >= 0) FLUSH_TO(curb, lg, lp, lmn, lmx);
        }
    }
    __syncthreads();
    if (tid < 32) {
        unsigned v = s_stats[tid];
        unsigned ident = (tid < 8 || tid >= 24) ? ENC_NEG_INF : ENC_POS_INF;
        if (v != ident) {
            if (tid >= 8 && tid < 24) atomicMin(&ws[tid], v);
            else                      atomicMax(&ws[tid], v);
        }
    }
}

__device__ __forceinline__ float point_loss(float p0, float p1, int s, float z, float mu) {
    float m   = fmaxf(p0, p1);
    float lse = m + logf(expf(p0 - m) + expf(p1 - m));
    float lpt = ((s == 0) ? p0 : p1) - lse;
    float pt  = expf(lpt);
    float om  = 1.0f - pt;
    float loss = -lpt * om * om;           // LOSS_WEIGHT=ALPHA=1, GAMMA=2
    float d  = z - mu;
    float cf = (z <= mu) ? 50.0f : 3.125f; // 1/(2*0.1^2), 1/(2*0.4^2)
    float w  = expf(-d * d * cf);
    if (z > mu && d > 0.8f) w = 0.1f;      // d > 2*0.4 -> MIN_VAL
    return loss * w;
}

__global__ __launch_bounds__(THREADS) void k_loss(
        const float* __restrict__ pred, const float* __restrict__ coord,
        const int* __restrict__ segment, const int* __restrict__ offset,
        unsigned* __restrict__ ws, float* __restrict__ out, int n, int nb) {
    __shared__ float s_mu[8];
    __shared__ float s_part[THREADS / 64];
    const int tid = threadIdx.x;
    int roff[8];
    #pragma unroll
    for (int j = 0; j < 8; ++j) roff[j] = (j < nb) ? offset[j] : 0x7FFFFFFF;
    if (tid < 8) {
        unsigned ug = ws[tid], up = ws[8 + tid];
        float g = dec_f(ug), p = dec_f(up);
        if (ug == ENC_NEG_INF) g = dec_f(ws[16 + tid]);  // no ground -> z.min
        if (up == ENC_POS_INF) p = dec_f(ws[24 + tid]);  // no plant  -> z.max
        s_mu[tid] = g + (p - g) * 0.5f;
    }
    __syncthreads();

    const int chunk = (n + (int)gridDim.x - 1) / (int)gridDim.x;
    const int start = blockIdx.x * chunk;
    const int end   = min(n, start + chunk);
    const float2* pred2 = (const float2*)pred;

    float lsum = 0.0f;
    if (start < end) {
        int ba = 0, bb = 0;
        #pragma unroll
        for (int j = 0; j < 8; ++j) { ba += (start >= roff[j]); bb += ((end - 1) >= roff[j]); }
        if (ba == bb) {
            const float mu = s_mu[ba];       // hoisted, no LDS in hot loop
            int i = start + tid;
            for (; i + (UNROLL - 1) * THREADS < end; i += UNROLL * THREADS) {
                float z[UNROLL]; int s[UNROLL]; float2 pp[UNROLL];
                #pragma unroll
                for (int k = 0; k < UNROLL; ++k) pp[k] = pred2[i + k * THREADS];
                #pragma unroll
                for (int k = 0; k < UNROLL; ++k) z[k] = coord[3 * (i + k * THREADS) + 2];
                #pragma unroll
                for (int k = 0; k < UNROLL; ++k) s[k] = segment[i + k * THREADS];
                #pragma unroll
                for (int k = 0; k < UNROLL; ++k)
                    lsum += point_loss(pp[k].x, pp[k].y, s[k], z[k], mu);
            }
            for (; i < end; i += THREADS) {
                float2 pp = pred2[i];
                lsum += point_loss(pp.x, pp.y, segment[i], coord[3 * i + 2], mu);
            }
        } else {
            for (int i = start + tid; i < end; i += THREADS) {
                int b = 0;
                #pragma unroll
                for (int j = 0; j < 8; ++j) b += (i >= roff[j]);
                float2 pp = pred2[i];
                lsum += point_loss(pp.x, pp.y, segment[i], coord[3 * i + 2], s_mu[b]);
            }
        }
    }

    #pragma unroll
    for (int off = 32; off > 0; off >>= 1) lsum += __shfl_down(lsum, off, 64);
    if ((tid & 63) == 0) s_part[tid >> 6] = lsum;
    __syncthreads();
    if (tid == 0) {
        float t = 0.0f;
        #pragma unroll
        for (int wv = 0; wv < THREADS / 64; ++wv) t += s_part[wv];
        double* acc = (double*)(ws + 32);
        atomicAdd(acc, (double)t);
        __threadfence();
        unsigned c = atomicAdd(&ws[34], 1u);
        if (c == (unsigned)gridDim.x - 1u) {       // last block finalizes
            double v = atomicAdd(acc, 0.0);        // coherent read via atomic
            out[0] = (float)(v / (double)n);
        }
    }
}

extern "C" void kernel_launch(void* const* d_in, const int* in_sizes, int n_in,
                              void* d_out, int out_size, void* d_ws, size_t ws_size,
                              hipStream_t stream) {
    const float* pred    = (const float*)d_in[0];
    const float* coord   = (const float*)d_in[1];
    const int*   segment = (const int*)d_in[2];
    const int*   offset  = (const int*)d_in[3];
    const int n  = in_sizes[2];
    const int nb = in_sizes[3];

    unsigned* ws = (unsigned*)d_ws;

    hipLaunchKernelGGL(k_init,  dim3(1), dim3(64), 0, stream, ws);
    hipLaunchKernelGGL(k_stats, dim3(NBLOCKS), dim3(THREADS), 0, stream,
                       coord, segment, offset, ws, n, nb);
    hipLaunchKernelGGL(k_loss,  dim3(NBLOCKS), dim3(THREADS), 0, stream,
                       pred, coord, segment, offset, ws, (float*)d_out, n, nb);
}